// Round 1
// baseline (41.827 us; speedup 1.0000x reference)
//
#include <hip/hip_runtime.h>
#include <math.h>

#define BB 16
#define NN 64
#define CC 256

__device__ __forceinline__ float gelu_exact(float x) {
    return 0.5f * x * (1.0f + erff(x * 0.70710678118654752440f));
}

// K1: per-element MLP -> etpp; s = tmp+p1+p2 -> Spos/Sneg row reductions; out0 = img copy
__global__ void k1_mlp_reduce(const float* __restrict__ img,
                              const float* __restrict__ tmp,
                              const float* __restrict__ p1,
                              const float* __restrict__ p2,
                              const float* __restrict__ w1,
                              const float* __restrict__ b1,
                              const float* __restrict__ w2,
                              const float* __restrict__ b2,
                              float* __restrict__ etpp,
                              float* __restrict__ Spos,
                              float* __restrict__ Sneg,
                              float* __restrict__ out0) {
    int bn = blockIdx.x;           // 0..B*N-1
    int c  = threadIdx.x;          // 0..255
    int idx = bn * CC + c;
    float t  = tmp[idx];
    float q1 = p1[idx];
    float q2 = p2[idx];
    float g  = img[idx];
    out0[idx] = g;

    float acc = b2[0];
    #pragma unroll
    for (int j = 0; j < 12; ++j) {
        float h = t * w1[j] + q1 * w1[12 + j] + q2 * w1[24 + j] + b1[j];
        acc += gelu_exact(h) * w2[j];
    }
    etpp[idx] = acc;

    float s  = t + q1 + q2;
    float s2 = s * s;
    float sp = (s >= 0.0f) ? s2 : 0.0f;
    float sn = (s < 0.0f)  ? s2 : 0.0f;

    // wave64 shuffle reduce, then cross-wave via LDS
    #pragma unroll
    for (int off = 32; off > 0; off >>= 1) {
        sp += __shfl_down(sp, off);
        sn += __shfl_down(sn, off);
    }
    __shared__ float swp[4], swn[4];
    int lane = threadIdx.x & 63;
    int wv   = threadIdx.x >> 6;
    if (lane == 0) { swp[wv] = sp; swn[wv] = sn; }
    __syncthreads();
    if (threadIdx.x == 0) {
        Spos[bn] = swp[0] + swp[1] + swp[2] + swp[3];
        Sneg[bn] = swn[0] + swn[1] + swn[2] + swn[3];
    }
}

// K2: M[b,c,x] = sum_n etpp[b,n,c] * img[b,n,x]   (batched GEMM, K=64)
__global__ void k2_gemm_M(const float* __restrict__ etpp,
                          const float* __restrict__ img,
                          float* __restrict__ M) {
    int b  = blockIdx.z;
    int c0 = blockIdx.y * 16;
    int x0 = blockIdx.x * 16;
    __shared__ float le[64][16];
    __shared__ float li[64][16];
    int tid = threadIdx.x;
    const float* eb = etpp + b * NN * CC;
    const float* ib = img  + b * NN * CC;
    #pragma unroll
    for (int k = 0; k < 4; ++k) {
        int idx = tid + k * 256;     // 0..1023
        int n  = idx >> 4;
        int cl = idx & 15;
        le[n][cl] = eb[n * CC + c0 + cl];
        li[n][cl] = ib[n * CC + x0 + cl];
    }
    __syncthreads();
    int tx = tid & 15, ty = tid >> 4;
    float acc = 0.0f;
    #pragma unroll
    for (int n = 0; n < 64; ++n) acc += le[n][ty] * li[n][tx];
    M[b * CC * CC + (c0 + ty) * CC + x0 + tx] = acc;
}

// K3: A = 3x3 stencil (cross-correlation, zero pad 1) of M, + gauss bias
__global__ void k3_conv(const float* __restrict__ M,
                        const float* __restrict__ gw,
                        const float* __restrict__ gb,
                        float* __restrict__ A) {
    int gid = blockIdx.x * blockDim.x + threadIdx.x;   // B*C*C
    int x = gid & 255;
    int c = (gid >> 8) & 255;
    int b = gid >> 16;
    const float* Mb = M + b * CC * CC;
    float acc = gb[0];
    #pragma unroll
    for (int dc = 0; dc < 3; ++dc) {
        int cc = c + dc - 1;
        if (cc < 0 || cc > 255) continue;
        #pragma unroll
        for (int dx = 0; dx < 3; ++dx) {
            int xx = x + dx - 1;
            if (xx < 0 || xx > 255) continue;
            acc += gw[dc * 3 + dx] * Mb[cc * 256 + xx];
        }
    }
    A[gid] = acc;
}

// K4: P[b,n,c] = sum_x img[b,n,x]*A[b,c,x]; res = max(P,img)*Spos + min(P,img)*Sneg
__global__ void k4_P_res(const float* __restrict__ A,
                         const float* __restrict__ img,
                         const float* __restrict__ Spos,
                         const float* __restrict__ Sneg,
                         float* __restrict__ out1) {
    int b  = blockIdx.z;
    int n0 = blockIdx.y * 16;
    int c0 = blockIdx.x * 16;
    __shared__ float li[16][65];
    __shared__ float la[16][65];
    int tid = threadIdx.x;
    const float* ib = img + b * NN * CC;
    const float* Ab = A   + b * CC * CC;
    int tx = tid & 15, ty = tid >> 4;
    float acc = 0.0f;
    for (int xc = 0; xc < 256; xc += 64) {
        #pragma unroll
        for (int k = 0; k < 4; ++k) {
            int idx = tid + k * 256;   // 0..1023
            int r  = idx >> 6;
            int xl = idx & 63;
            li[r][xl] = ib[(n0 + r) * CC + xc + xl];
            la[r][xl] = Ab[(c0 + r) * CC + xc + xl];
        }
        __syncthreads();
        #pragma unroll
        for (int x = 0; x < 64; ++x) acc += li[ty][x] * la[tx][x];
        __syncthreads();
    }
    int n = n0 + ty, c = c0 + tx;
    int idx = b * NN * CC + n * CC + c;
    float g  = ib[n * CC + c];
    float sp = Spos[b * NN + n];
    float sn = Sneg[b * NN + n];
    out1[idx] = fmaxf(acc, g) * sp + fminf(acc, g) * sn;
}

extern "C" void kernel_launch(void* const* d_in, const int* in_sizes, int n_in,
                              void* d_out, int out_size, void* d_ws, size_t ws_size,
                              hipStream_t stream) {
    const float* img = (const float*)d_in[0];
    const float* tmp = (const float*)d_in[1];
    const float* p1  = (const float*)d_in[2];
    const float* p2  = (const float*)d_in[3];
    const float* w1  = (const float*)d_in[4];
    const float* b1  = (const float*)d_in[5];
    const float* w2  = (const float*)d_in[6];
    const float* b2  = (const float*)d_in[7];
    const float* gw  = (const float*)d_in[8];
    const float* gb  = (const float*)d_in[9];

    float* out0 = (float*)d_out;                 // image_embedding passthrough
    float* out1 = out0 + BB * NN * CC;           // res

    float* ws   = (float*)d_ws;
    float* etpp = ws;                            // B*N*C   = 262144
    float* Spos = etpp + BB * NN * CC;           // B*N     = 1024
    float* Sneg = Spos + BB * NN;                // B*N     = 1024
    float* M    = Sneg + BB * NN;                // B*C*C   = 1048576
    float* A    = M + BB * CC * CC;              // B*C*C   = 1048576

    k1_mlp_reduce<<<BB * NN, 256, 0, stream>>>(img, tmp, p1, p2, w1, b1, w2, b2,
                                               etpp, Spos, Sneg, out0);
    k2_gemm_M<<<dim3(16, 16, 16), 256, 0, stream>>>(etpp, img, M);
    k3_conv<<<4096, 256, 0, stream>>>(M, gw, gb, A);
    k4_P_res<<<dim3(16, 4, 16), 256, 0, stream>>>(A, img, Spos, Sneg, out1);
}